// Round 10
// baseline (426.812 us; speedup 1.0000x reference)
//
#include <hip/hip_runtime.h>
#include <math.h>

#define HW    409600      // 640*640
#define HW4   102400      // quads per batch plane
#define BATCH 8
#define NLAB  33
#define CH    1024        // pixels per block chunk
#define NCH   (HW/CH)     // 400 blocks per batch
#define NREP  4           // LDS bin replicas (per 16-lane cluster)
#define RS    201         // replica stride (33*6=198 fields + pad)
#define POISON32 0xAAAAAAAAu
// ws float-offset layout:
#define MEANS_OFF 0                        // [8][168]: mean[132], invci@132..164
#define BL_OFF    1792                     // [8] per-batch losses
#define P2_OFF    2048                     // [8][512] pass2 partials
#define CNT_OFF   6400                     // u32 counters (257), poison-initialized
#define AWS_OFF   7168                     // [8][208] atomic-fallback record
#define P1_OFF    12288                    // [3200][200] contiguous records
#define LABS_OFF_F (P1_OFF + BATCH*NCH*200)          // 652288
#define NEED_FUSED ((size_t)LABS_OFF_F * 4 + (size_t)BATCH * HW4 * 4)

__device__ __forceinline__ float getc(const float4& v, int e) {
    return (e == 0) ? v.x : (e == 1) ? v.y : (e == 2) ? v.z : v.w;
}
__device__ __forceinline__ float wave_sum(float v) {
    #pragma unroll
    for (int o = 32; o > 0; o >>= 1) v += __shfl_xor(v, o);
    return v;
}

// async global->LDS: 16B per lane, wave-uniform LDS base + lane*16
__device__ __forceinline__ void stage16(const unsigned* g, float* l, int lane) {
#if defined(__has_builtin) && __has_builtin(__builtin_amdgcn_global_load_lds)
    __builtin_amdgcn_global_load_lds(
        (const __attribute__((address_space(1))) unsigned int*)(g + 4 * lane),
        (__attribute__((address_space(3))) unsigned int*)l, 16, 0, 0);
#else
    ((uint4*)l)[lane] = ((const uint4*)g)[lane];
#endif
}

__device__ __forceinline__ void acc1(int l, bool k,
                                     float x0, float x1, float x2, float x3,
                                     float* mb) {
    if (l) {
        float* bb = mb + l * 6;
        atomicAdd(bb + 5, 1.f);          // cnt_i
        if (k) {
            atomicAdd(bb + 0, x0);
            atomicAdd(bb + 1, x1);
            atomicAdd(bb + 2, x2);
            atomicAdd(bb + 3, x3);
            atomicAdd(bb + 4, 1.f);      // cnt_k
        }
    }
}

// ================= FUSED PATH (2 launches) =================

// pass1f: DMA-staged binning -> record store -> ticket -> last block reduces means
__global__ __launch_bounds__(256, 5) void pass1f(const float* __restrict__ emb,
                                                 const int*   __restrict__ inst,
                                                 const float* __restrict__ kern,
                                                 const float* __restrict__ tmask,
                                                 float*       __restrict__ ws,
                                                 unsigned*    __restrict__ labs) {
    __shared__ float stage[7 * CH];      // 28 KB (aliased as raw[] in last block)
    __shared__ float bins[NREP][RS];     // 3.2 KB
    __shared__ unsigned isLastS;
    const int t = threadIdx.x, bx = blockIdx.x, b = blockIdx.y;
    const int wave = t >> 6, lane = t & 63;

    const size_t pixb = (size_t)bx * CH;
    const unsigned* gs[7];
    gs[0] = (const unsigned*)(inst  + (size_t)b * HW + pixb);
    gs[1] = (const unsigned*)(tmask + (size_t)b * HW + pixb);
    gs[2] = (const unsigned*)(kern  + (size_t)b * HW + pixb);
    #pragma unroll
    for (int d = 0; d < 4; ++d)
        gs[3 + d] = (const unsigned*)(emb + ((size_t)b * 4 + d) * HW + pixb);

    #pragma unroll
    for (int i = 0; i < 7; ++i) {
        int tau = wave * 7 + i;
        int s = tau >> 2, p = tau & 3;
        stage16(gs[s] + p * 256, &stage[s * CH + p * 256], lane);
    }

    float* mb = bins[(t >> 4) & (NREP - 1)];
    for (int i = t; i < NREP * RS; i += 256) (&bins[0][0])[i] = 0.f;
    __syncthreads();                     // drains DMA vmcnt + lgkm

    int4   iv = ((const int4*)  (stage + 0 * CH))[t];
    float4 tv = ((const float4*)(stage + 1 * CH))[t];
    float4 kv = ((const float4*)(stage + 2 * CH))[t];
    float4 x0 = ((const float4*)(stage + 3 * CH))[t];
    float4 x1 = ((const float4*)(stage + 4 * CH))[t];
    float4 x2 = ((const float4*)(stage + 5 * CH))[t];
    float4 x3 = ((const float4*)(stage + 6 * CH))[t];

    int l0 = (tv.x > 0.5f) ? iv.x : 0;
    int l1 = (tv.y > 0.5f) ? iv.y : 0;
    int l2 = (tv.z > 0.5f) ? iv.z : 0;
    int l3 = (tv.w > 0.5f) ? iv.w : 0;
    labs[(size_t)b * HW4 + (size_t)bx * (CH / 4) + t] =
        (unsigned)l0 | ((unsigned)l1 << 8) |
        ((unsigned)l2 << 16) | ((unsigned)l3 << 24);

    acc1(l0, kv.x > 0.5f, x0.x, x1.x, x2.x, x3.x, mb);
    acc1(l1, kv.y > 0.5f, x0.y, x1.y, x2.y, x3.y, mb);
    acc1(l2, kv.z > 0.5f, x0.z, x1.z, x2.z, x3.z, mb);
    acc1(l3, kv.w > 0.5f, x0.w, x1.w, x2.w, x3.w, mb);
    __syncthreads();

    if (t < 198) {
        float v = 0.f;
        #pragma unroll
        for (int r = 0; r < NREP; ++r) v += bins[r][t];
        ws[P1_OFF + ((size_t)b * NCH + bx) * 200 + t] = v;
    }
    __syncthreads();                     // all record stores vmcnt-drained
    if (t == 0) {
        __threadfence();                 // flush to device-coherent point
        unsigned* cnt = (unsigned*)(ws + CNT_OFF);
        unsigned old = __hip_atomic_fetch_add(&cnt[b * 16], 1u,
                                              __ATOMIC_ACQ_REL,
                                              __HIP_MEMORY_SCOPE_AGENT);
        isLastS = (old == POISON32 + (unsigned)(NCH - 1)) ? 1u : 0u;
    }
    __syncthreads();
    if (!isLastS) return;

    // last block of batch b: reduce 400 records -> means/invci
    float* raw = stage;                  // stage no longer needed
    if (t < 198) {
        const float* p = ws + P1_OFF + (size_t)b * NCH * 200 + t;
        float a0 = 0, a1 = 0, a2 = 0, a3 = 0, a4 = 0, a5 = 0, a6 = 0, a7 = 0;
        for (int i = 0; i < NCH; i += 8) {
            a0 += p[(i + 0) * 200]; a1 += p[(i + 1) * 200];
            a2 += p[(i + 2) * 200]; a3 += p[(i + 3) * 200];
            a4 += p[(i + 4) * 200]; a5 += p[(i + 5) * 200];
            a6 += p[(i + 6) * 200]; a7 += p[(i + 7) * 200];
        }
        raw[t] = ((a0 + a1) + (a2 + a3)) + ((a4 + a5) + (a6 + a7));
    }
    __syncthreads();
    float* mm = ws + MEANS_OFF + b * 168;
    if (t < NLAB) {
        float ck = raw[t * 6 + 4], ci = raw[t * 6 + 5];
        float inv = 1.f / fmaxf(ck, 1.f);
        float z = (t == 0) ? 0.f : 1.f;
        mm[t * 4 + 0] = z * raw[t * 6 + 0] * inv;
        mm[t * 4 + 1] = z * raw[t * 6 + 1] * inv;
        mm[t * 4 + 2] = z * raw[t * 6 + 2] * inv;
        mm[t * 4 + 3] = z * raw[t * 6 + 3] * inv;
        mm[132 + t]   = 1.f / fmaxf(ci, 1.f);
    }
    // visible to pass2f via kernel-boundary flush
}

// pass2f: DMA-staged val partial -> ticket -> last block does batch loss -> global ticket -> out
__global__ __launch_bounds__(256, 7) void pass2f(const float* __restrict__ emb,
                                                 float*       __restrict__ ws,
                                                 const unsigned* __restrict__ labs,
                                                 float*       __restrict__ out) {
    __shared__ float  stage[4 * CH + CH / 4];  // 17 KB
    __shared__ float4 means4[NLAB];
    __shared__ float  invci[NLAB];
    __shared__ float  red[4];
    __shared__ unsigned isLastS;
    const int t = threadIdx.x, bx = blockIdx.x, b = blockIdx.y;
    const int wave = t >> 6, lane = t & 63;
    const size_t pixb = (size_t)bx * CH;

    const unsigned* gp[5];
    #pragma unroll
    for (int d = 0; d < 4; ++d)
        gp[d] = (const unsigned*)(emb + ((size_t)b * 4 + d) * HW + pixb);
    gp[4] = labs + (size_t)b * HW4 + (size_t)bx * (CH / 4);
    for (int tau = wave; tau < 17; tau += 4) {
        if (tau < 16) {
            int s = tau >> 2, p = tau & 3;
            stage16(gp[s] + p * 256, &stage[s * CH + p * 256], lane);
        } else {
            stage16(gp[4], &stage[4 * CH], lane);
        }
    }

    const float* mm = ws + MEANS_OFF + b * 168;
    if (t < NLAB) {
        means4[t] = ((const float4*)mm)[t];
        invci[t]  = mm[132 + t];
    }
    __syncthreads();

    unsigned pk = ((const unsigned*)(stage + 4 * CH))[t];
    float4 x0 = ((const float4*)(stage + 0 * CH))[t];
    float4 x1 = ((const float4*)(stage + 1 * CH))[t];
    float4 x2 = ((const float4*)(stage + 2 * CH))[t];
    float4 x3 = ((const float4*)(stage + 3 * CH))[t];

    float acc = 0.f;
    #pragma unroll
    for (int e = 0; e < 4; ++e) {
        int l = (pk >> (8 * e)) & 255;
        if (l) {
            float4 m = means4[l];
            float d0 = getc(x0, e) - m.x, d1 = getc(x1, e) - m.y;
            float d2 = getc(x2, e) - m.z, d3 = getc(x3, e) - m.w;
            float dist = sqrtf(d0 * d0 + d1 * d1 + d2 * d2 + d3 * d3);
            float u = fmaxf(dist - 0.5f, 0.f);
            acc += __logf(u * u + 1.f) * invci[l];
        }
    }

    acc = wave_sum(acc);
    if ((t & 63) == 0) red[t >> 6] = acc;
    __syncthreads();
    unsigned* cnt = (unsigned*)(ws + CNT_OFF);
    if (t == 0) {
        ws[P2_OFF + b * 512 + bx] = red[0] + red[1] + red[2] + red[3];
        __threadfence();
        unsigned old = __hip_atomic_fetch_add(&cnt[128 + b * 16], 1u,
                                              __ATOMIC_ACQ_REL,
                                              __HIP_MEMORY_SCOPE_AGENT);
        isLastS = (old == POISON32 + (unsigned)(NCH - 1)) ? 1u : 0u;
    }
    __syncthreads();
    if (!isLastS) return;

    // last block of batch b: full per-batch loss (means4/invci already in LDS)
    float pa = 0.f;
    for (int i = t; i < NCH; i += 256) pa += ws[P2_OFF + b * 512 + i];
    pa *= (1.f / 32.f);                                   // l_agg
    float disp = 0.f;
    for (int p = t; p < 1024; p += 256) {
        int i = p >> 5, j = p & 31;
        if (i != j) {
            float4 mi = means4[i + 1], mj = means4[j + 1];
            float d0 = mi.x - mj.x, d1 = mi.y - mj.y;
            float d2 = mi.z - mj.z, d3 = mi.w - mj.w;
            float pd = sqrtf(d0 * d0 + d1 * d1 + d2 * d2 + d3 * d3);
            float u = fmaxf(3.0f - pd, 0.f);
            disp += __logf(u * u + 1.f);
        }
    }
    disp *= 1.f / 992.f;                                  // 32*31
    float regp = 0.f;
    if (t >= 1 && t < NLAB) {
        float4 m = means4[t];
        float n2 = m.x * m.x + m.y * m.y + m.z * m.z + m.w * m.w;
        regp = __logf(sqrtf(n2) + 1.f) * (0.001f / 33.f);
    }
    float v = wave_sum(pa + disp + regp);
    if ((t & 63) == 0) red[t >> 6] = v;
    __syncthreads();
    if (t == 0) {
        ws[BL_OFF + b] = red[0] + red[1] + red[2] + red[3];
        __threadfence();
        unsigned old = __hip_atomic_fetch_add(&cnt[256], 1u,
                                              __ATOMIC_ACQ_REL,
                                              __HIP_MEMORY_SCOPE_AGENT);
        if (old == POISON32 + (unsigned)(BATCH - 1)) {
            float tot = 0.f;
            #pragma unroll
            for (int i = 0; i < BATCH; ++i) tot += ws[BL_OFF + i];
            out[0] = tot * (1.f / BATCH);
        }
    }
}

// ================= FALLBACK PATH (tiny ws): R9 4-kernel chain =================

__global__ void init_aws(float* ws) {
    int i = blockIdx.x * 256 + threadIdx.x;
    if (i < BATCH * 208) ws[AWS_OFF + i] = 0.f;
}

__global__ __launch_bounds__(256, 5) void pass1_fb(const float* __restrict__ emb,
                                                   const int*   __restrict__ inst,
                                                   const float* __restrict__ kern,
                                                   const float* __restrict__ tmask,
                                                   float*       __restrict__ ws) {
    __shared__ float bins[NREP][RS];
    const int t = threadIdx.x, bx = blockIdx.x, b = blockIdx.y;
    float* mb = bins[(t >> 4) & (NREP - 1)];
    for (int i = t; i < NREP * RS; i += 256) (&bins[0][0])[i] = 0.f;
    __syncthreads();
    const float4* emb4  = (const float4*)(emb + (size_t)b * 4 * HW);
    const int4*   inst4 = (const int4*)(inst + (size_t)b * HW);
    const float4* kern4 = (const float4*)(kern + (size_t)b * HW);
    const float4* tm4   = (const float4*)(tmask + (size_t)b * HW);
    const int g = bx * 256 + t;
    int4 iv = inst4[g]; float4 tv = tm4[g]; float4 kv = kern4[g];
    float4 x0 = emb4[g], x1 = emb4[g + HW4], x2 = emb4[g + 2 * HW4], x3 = emb4[g + 3 * HW4];
    int l0 = (tv.x > 0.5f) ? iv.x : 0, l1 = (tv.y > 0.5f) ? iv.y : 0;
    int l2 = (tv.z > 0.5f) ? iv.z : 0, l3 = (tv.w > 0.5f) ? iv.w : 0;
    acc1(l0, kv.x > 0.5f, x0.x, x1.x, x2.x, x3.x, mb);
    acc1(l1, kv.y > 0.5f, x0.y, x1.y, x2.y, x3.y, mb);
    acc1(l2, kv.z > 0.5f, x0.z, x1.z, x2.z, x3.z, mb);
    acc1(l3, kv.w > 0.5f, x0.w, x1.w, x2.w, x3.w, mb);
    __syncthreads();
    if (t < 198) {
        float v = 0.f;
        #pragma unroll
        for (int r = 0; r < NREP; ++r) v += bins[r][t];
        if (v != 0.f) atomicAdd(ws + AWS_OFF + b * 208 + t, v);
    }
}

__global__ __launch_bounds__(256) void reduce_means_fb(float* __restrict__ ws) {
    __shared__ float raw[200];
    const int t = threadIdx.x, b = blockIdx.x;
    if (t < 198) raw[t] = ws[AWS_OFF + b * 208 + t];
    __syncthreads();
    float* mm = ws + MEANS_OFF + b * 168;
    if (t < NLAB) {
        float ck = raw[t * 6 + 4], ci = raw[t * 6 + 5];
        float inv = 1.f / fmaxf(ck, 1.f);
        float z = (t == 0) ? 0.f : 1.f;
        mm[t * 4 + 0] = z * raw[t * 6 + 0] * inv;
        mm[t * 4 + 1] = z * raw[t * 6 + 1] * inv;
        mm[t * 4 + 2] = z * raw[t * 6 + 2] * inv;
        mm[t * 4 + 3] = z * raw[t * 6 + 3] * inv;
        mm[132 + t]   = 1.f / fmaxf(ci, 1.f);
    }
}

__global__ __launch_bounds__(256, 7) void pass2_fb(const float* __restrict__ emb,
                                                   const int*   __restrict__ inst,
                                                   const float* __restrict__ tmask,
                                                   float*       __restrict__ ws) {
    __shared__ float4 means4[NLAB];
    __shared__ float  invci[NLAB];
    __shared__ float  red[4];
    const int t = threadIdx.x, bx = blockIdx.x, b = blockIdx.y;
    const float4* emb4  = (const float4*)(emb + (size_t)b * 4 * HW);
    const int4*   inst4 = (const int4*)(inst + (size_t)b * HW);
    const float4* tm4   = (const float4*)(tmask + (size_t)b * HW);
    const int g = bx * 256 + t;
    int4 iv = inst4[g]; float4 tv = tm4[g];
    float4 x0 = emb4[g], x1 = emb4[g + HW4], x2 = emb4[g + 2 * HW4], x3 = emb4[g + 3 * HW4];
    const float* mm = ws + MEANS_OFF + b * 168;
    if (t < NLAB) { means4[t] = ((const float4*)mm)[t]; invci[t] = mm[132 + t]; }
    __syncthreads();
    unsigned pk = (unsigned)((tv.x > 0.5f) ? iv.x : 0)        |
                  ((unsigned)((tv.y > 0.5f) ? iv.y : 0) << 8) |
                  ((unsigned)((tv.z > 0.5f) ? iv.z : 0) << 16)|
                  ((unsigned)((tv.w > 0.5f) ? iv.w : 0) << 24);
    float acc = 0.f;
    #pragma unroll
    for (int e = 0; e < 4; ++e) {
        int l = (pk >> (8 * e)) & 255;
        if (l) {
            float4 m = means4[l];
            float d0 = getc(x0, e) - m.x, d1 = getc(x1, e) - m.y;
            float d2 = getc(x2, e) - m.z, d3 = getc(x3, e) - m.w;
            float dist = sqrtf(d0 * d0 + d1 * d1 + d2 * d2 + d3 * d3);
            float u = fmaxf(dist - 0.5f, 0.f);
            acc += __logf(u * u + 1.f) * invci[l];
        }
    }
    acc = wave_sum(acc);
    if ((t & 63) == 0) red[t >> 6] = acc;
    __syncthreads();
    if (t == 0) ws[P2_OFF + b * 512 + bx] = red[0] + red[1] + red[2] + red[3];
}

__global__ __launch_bounds__(256) void final_fb(const float* __restrict__ ws,
                                                float* __restrict__ out, int nbx) {
    __shared__ float4 means4[NLAB];
    __shared__ float  red[4];
    const int t = threadIdx.x;
    float total = 0.f;
    for (int b = 0; b < BATCH; ++b) {
        __syncthreads();
        const float* mm = ws + MEANS_OFF + b * 168;
        if (t < NLAB) means4[t] = ((const float4*)mm)[t];
        __syncthreads();
        float pa = 0.f;
        for (int i = t; i < nbx; i += 256) pa += ws[P2_OFF + b * 512 + i];
        pa *= (1.f / 32.f);
        float disp = 0.f;
        for (int p = t; p < 1024; p += 256) {
            int i = p >> 5, j = p & 31;
            if (i != j) {
                float4 mi = means4[i + 1], mj = means4[j + 1];
                float d0 = mi.x - mj.x, d1 = mi.y - mj.y;
                float d2 = mi.z - mj.z, d3 = mi.w - mj.w;
                float pd = sqrtf(d0 * d0 + d1 * d1 + d2 * d2 + d3 * d3);
                float u = fmaxf(3.0f - pd, 0.f);
                disp += __logf(u * u + 1.f);
            }
        }
        disp *= 1.f / 992.f;
        float regp = 0.f;
        if (t >= 1 && t < NLAB) {
            float4 m = means4[t];
            float n2 = m.x * m.x + m.y * m.y + m.z * m.z + m.w * m.w;
            regp = __logf(sqrtf(n2) + 1.f) * (0.001f / 33.f);
        }
        float v = wave_sum(pa + disp + regp);
        if ((t & 63) == 0) red[t >> 6] = v;
        __syncthreads();
        if (t == 0) total += red[0] + red[1] + red[2] + red[3];
    }
    if (t == 0) out[0] = total * (1.f / BATCH);
}

extern "C" void kernel_launch(void* const* d_in, const int* in_sizes, int n_in,
                              void* d_out, int out_size, void* d_ws, size_t ws_size,
                              hipStream_t stream) {
    const float* emb   = (const float*)d_in[0];
    const int*   inst  = (const int*)  d_in[1];
    const float* kern  = (const float*)d_in[2];
    const float* tmask = (const float*)d_in[3];
    float* ws  = (float*)d_ws;
    float* out = (float*)d_out;

    if (ws_size >= NEED_FUSED) {
        unsigned* labs = (unsigned*)(ws + LABS_OFF_F);
        dim3 grid(NCH, BATCH);
        pass1f<<<grid, 256, 0, stream>>>(emb, inst, kern, tmask, ws, labs);
        pass2f<<<grid, 256, 0, stream>>>(emb, ws, labs, out);
    } else {
        init_aws<<<dim3((BATCH * 208 + 255) / 256), 256, 0, stream>>>(ws);
        dim3 grid(HW4 / 256, BATCH);
        pass1_fb<<<grid, 256, 0, stream>>>(emb, inst, kern, tmask, ws);
        reduce_means_fb<<<BATCH, 256, 0, stream>>>(ws);
        pass2_fb<<<grid, 256, 0, stream>>>(emb, inst, tmask, ws);
        final_fb<<<1, 256, 0, stream>>>(ws, out, HW4 / 256);
    }
}